// Round 5
// baseline (260.487 us; speedup 1.0000x reference)
//
#include <hip/hip_runtime.h>

#define BATCH 8
#define NROW  2048
#define DIM   512

typedef __bf16 bf16x8 __attribute__((ext_vector_type(8)));
typedef float  f32x4  __attribute__((ext_vector_type(4)));
typedef unsigned short u16x8 __attribute__((ext_vector_type(8)));

// round-to-nearest-even fp32 -> bf16 bits (same numerics as passing rounds)
__device__ __forceinline__ unsigned short f2bf(float f) {
    unsigned int u = __float_as_uint(f);
    u += 0x7FFFu + ((u >> 16) & 1u);
    return (unsigned short)(u >> 16);
}

// ---------------- fused cast+norm+GEMM: 256x256 tile, BK=64, 8-wave, --------
// 8-phase pipeline, reg-staged fp32->bf16 (T14 issue-early/write-late).
// LDS: 8 half-buffers of 16KB: index (par<<2)|(X<<1)|k, X: A=0,B=1.
// Half layout: 16 subtiles [16 r][32 bf16] of 1024B with st_16x32 swizzle,
// materialized by pre-swizzled k-offset vc on the SOURCE side (same bytes as
// the verified round-4 gload_lds layout; read side rb unchanged).

// load 16 fp32 (2 rows x 8) for half (X,K) of tile T into slot S
#define LOADH(Xf, K, T, S) {                                                 \
    const float* p_ = (Xf) + (size_t)vr0 * DIM + (T) * 64 + (K) * 32 + vc;   \
    st[S][0] = *(const f32x4*)p_;                                            \
    st[S][1] = *(const f32x4*)(p_ + 4);                                      \
    const float* q_ = p_ + (size_t)128 * DIM;                                \
    st[S][2] = *(const f32x4*)q_;                                            \
    st[S][3] = *(const f32x4*)(q_ + 4);                                      \
  }

// convert slot S -> bf16, accumulate sumsq, ds_write to half (Xi,K) of tile T
#define WRITEH(Xi, K, T, S, SSa, SSb) {                                      \
    char* hb_ = sm + (((((T) & 1) << 2) | ((Xi) << 1) | (K)) << 14);         \
    u16x8 w0_, w1_;                                                          \
    _Pragma("unroll")                                                        \
    for (int j_ = 0; j_ < 4; ++j_) {                                         \
      float v0_ = st[S][0][j_], v1_ = st[S][1][j_];                          \
      float v2_ = st[S][2][j_], v3_ = st[S][3][j_];                          \
      SSa += v0_ * v0_ + v1_ * v1_;                                          \
      SSb += v2_ * v2_ + v3_ * v3_;                                          \
      w0_[j_] = f2bf(v0_); w0_[j_ + 4] = f2bf(v1_);                          \
      w1_[j_] = f2bf(v2_); w1_[j_ + 4] = f2bf(v3_);                          \
    }                                                                        \
    *(u16x8*)(hb_ + wave * 1024 + lane * 16) = w0_;                          \
    *(u16x8*)(hb_ + 8192 + wave * 1024 + lane * 16) = w1_;                   \
  }

#define LDSA(M, KS, PAR) \
  (*(const bf16x8*)(sm + ((((PAR) << 2) | (KS)) << 14) + ((wm * 8 + (M)) << 10) + rb))
#define LDSB(N, KS, PAR) \
  (*(const bf16x8*)(sm + ((((PAR) << 2) | 2 | (KS)) << 14) + ((wn * 4 + (N)) << 10) + rb))

#define PHASE(PAR, MH, KS, READB, LSTMT, WSTMT)                              \
  { __builtin_amdgcn_sched_barrier(0);                                       \
    bf16x8 a0 = LDSA((MH)*4+0, KS, PAR), a1 = LDSA((MH)*4+1, KS, PAR),       \
           a2 = LDSA((MH)*4+2, KS, PAR), a3 = LDSA((MH)*4+3, KS, PAR);       \
    if (READB) { bfr[0] = LDSB(0, KS, PAR); bfr[1] = LDSB(1, KS, PAR);       \
                 bfr[2] = LDSB(2, KS, PAR); bfr[3] = LDSB(3, KS, PAR); }     \
    LSTMT;                                                                   \
    WSTMT;                                                                   \
    asm volatile("s_waitcnt lgkmcnt(0)" ::: "memory");                       \
    __builtin_amdgcn_sched_barrier(0);                                       \
    __builtin_amdgcn_s_barrier();                                            \
    __builtin_amdgcn_s_setprio(1);                                           \
    _Pragma("unroll")                                                        \
    for (int n = 0; n < 4; ++n) {                                            \
      acc[(MH)*4+0][n] = __builtin_amdgcn_mfma_f32_16x16x32_bf16(a0, bfr[n], acc[(MH)*4+0][n], 0, 0, 0); \
      acc[(MH)*4+1][n] = __builtin_amdgcn_mfma_f32_16x16x32_bf16(a1, bfr[n], acc[(MH)*4+1][n], 0, 0, 0); \
      acc[(MH)*4+2][n] = __builtin_amdgcn_mfma_f32_16x16x32_bf16(a2, bfr[n], acc[(MH)*4+2][n], 0, 0, 0); \
      acc[(MH)*4+3][n] = __builtin_amdgcn_mfma_f32_16x16x32_bf16(a3, bfr[n], acc[(MH)*4+3][n], 0, 0, 0); \
    }                                                                        \
    __builtin_amdgcn_s_setprio(0);                                           \
    __builtin_amdgcn_sched_barrier(0);                                       \
    __builtin_amdgcn_s_barrier(); }

__global__ __launch_bounds__(512, 2) void fused_kernel(
    const float* __restrict__ x, const float* __restrict__ y,
    float* __restrict__ out)
{
    extern __shared__ char sm[];
    const int tid  = threadIdx.x;
    const int lane = tid & 63;
    const int wave = tid >> 6;
    const int wm   = wave >> 2;     // 0..1  (M half)
    const int wn   = wave & 3;      // 0..3  (N quarter)

    // bijective XCD swizzle: nwg=512, 8 XCDs, 64 blocks each -> batch b == XCD
    const int bid = blockIdx.x;
    const int wg  = (bid & 7) * 64 + (bid >> 3);
    const int b   = wg >> 6;
    const int bm  = (wg >> 3) & 7;
    const int bn  = wg & 7;

    const float* Af = x + ((size_t)b * NROW + bm * 256) * DIM;
    const float* Bf = y + ((size_t)b * NROW + bn * 256) * DIM;

    // staging geometry (identical LDS bytes as the verified gload_lds layout)
    const int vr0 = wave * 16 + (lane >> 2);                     // rows 0..127
    const int vc  = ((lane & 3) * 8) ^ ((lane & 32) ? 16 : 0);   // pre-swizzled k
    // read per-lane base byte within a half-buffer subtile-row
    const int rb  = (lane & 15) * 64 + (((lane >> 4) * 16) ^ ((lane & 8) ? 32 : 0));

    f32x4 st[3][4];
    float ssA0 = 0.f, ssA1 = 0.f, ssB0 = 0.f, ssB1 = 0.f;
    f32x4 acc_init; // silence nothing; accumulators below
    (void)acc_init;
    f32x4 acc[8][4] = {};
    bf16x8 bfr[4];

    // ---- prologue: stage tile0 fully + Bk0/Ak0/Bk1 of tile1 ---------------
    LOADH(Bf, 0, 0, 0) LOADH(Af, 0, 0, 1)
    WRITEH(1, 0, 0, 0, ssB0, ssB1) WRITEH(0, 0, 0, 1, ssA0, ssA1)
    LOADH(Bf, 1, 0, 0) LOADH(Af, 1, 0, 1)
    WRITEH(1, 1, 0, 0, ssB0, ssB1) WRITEH(0, 1, 0, 1, ssA0, ssA1)
    LOADH(Bf, 0, 1, 0) LOADH(Af, 0, 1, 1) LOADH(Bf, 1, 1, 2)
    WRITEH(1, 1, 1, 2, ssB0, ssB1)            // Bk1(1); Bk0(1)/Ak0(1) stay in regs
    asm volatile("s_waitcnt lgkmcnt(0)" ::: "memory");
    __builtin_amdgcn_sched_barrier(0);
    __builtin_amdgcn_s_barrier();

    // ---- main loop: 32 phases, load@g -> write@g+2, slots (g+1)%3/(g-1)%3 -
    // i = 0 (tiles 0,1; prefetch 2,3)
    PHASE(0,0,0,1, LOADH(Af,1,1,2), WRITEH(1,0,1, 0, ssB0,ssB1))   // g1
    PHASE(0,1,0,0, LOADH(Bf,0,2,0), WRITEH(0,0,1, 1, ssA0,ssA1))   // g2
    PHASE(0,0,1,1, LOADH(Af,0,2,1), WRITEH(0,1,1, 2, ssA0,ssA1))   // g3
    PHASE(0,1,1,0, LOADH(Bf,1,2,2), WRITEH(1,0,2, 0, ssB0,ssB1))   // g4
    PHASE(1,0,0,1, LOADH(Af,1,2,0), WRITEH(0,0,2, 1, ssA0,ssA1))   // g5
    PHASE(1,1,0,0, LOADH(Bf,0,3,1), WRITEH(1,1,2, 2, ssB0,ssB1))   // g6
    PHASE(1,0,1,1, LOADH(Af,0,3,2), WRITEH(0,1,2, 0, ssA0,ssA1))   // g7
    PHASE(1,1,1,0, LOADH(Bf,1,3,0), WRITEH(1,0,3, 1, ssB0,ssB1))   // g8
    // i = 1 (tiles 2,3; prefetch 4,5)
    PHASE(0,0,0,1, LOADH(Af,1,3,1), WRITEH(0,0,3, 2, ssA0,ssA1))   // g9
    PHASE(0,1,0,0, LOADH(Bf,0,4,2), WRITEH(1,1,3, 0, ssB0,ssB1))   // g10
    PHASE(0,0,1,1, LOADH(Af,0,4,0), WRITEH(0,1,3, 1, ssA0,ssA1))   // g11
    PHASE(0,1,1,0, LOADH(Bf,1,4,1), WRITEH(1,0,4, 2, ssB0,ssB1))   // g12
    PHASE(1,0,0,1, LOADH(Af,1,4,2), WRITEH(0,0,4, 0, ssA0,ssA1))   // g13
    PHASE(1,1,0,0, LOADH(Bf,0,5,0), WRITEH(1,1,4, 1, ssB0,ssB1))   // g14
    PHASE(1,0,1,1, LOADH(Af,0,5,1), WRITEH(0,1,4, 2, ssA0,ssA1))   // g15
    PHASE(1,1,1,0, LOADH(Bf,1,5,2), WRITEH(1,0,5, 0, ssB0,ssB1))   // g16
    // i = 2 (tiles 4,5; prefetch 6,7)
    PHASE(0,0,0,1, LOADH(Af,1,5,0), WRITEH(0,0,5, 1, ssA0,ssA1))   // g17
    PHASE(0,1,0,0, LOADH(Bf,0,6,1), WRITEH(1,1,5, 2, ssB0,ssB1))   // g18
    PHASE(0,0,1,1, LOADH(Af,0,6,2), WRITEH(0,1,5, 0, ssA0,ssA1))   // g19
    PHASE(0,1,1,0, LOADH(Bf,1,6,0), WRITEH(1,0,6, 1, ssB0,ssB1))   // g20
    PHASE(1,0,0,1, LOADH(Af,1,6,1), WRITEH(0,0,6, 2, ssA0,ssA1))   // g21
    PHASE(1,1,0,0, LOADH(Bf,0,7,2), WRITEH(1,1,6, 0, ssB0,ssB1))   // g22
    PHASE(1,0,1,1, LOADH(Af,0,7,0), WRITEH(0,1,6, 1, ssA0,ssA1))   // g23
    PHASE(1,1,1,0, LOADH(Bf,1,7,1), WRITEH(1,0,7, 2, ssB0,ssB1))   // g24
    // i = 3 (tiles 6,7; drain)
    PHASE(0,0,0,1, LOADH(Af,1,7,2), WRITEH(0,0,7, 0, ssA0,ssA1))   // g25
    PHASE(0,1,0,0, ,                WRITEH(1,1,7, 1, ssB0,ssB1))   // g26
    PHASE(0,0,1,1, ,                WRITEH(0,1,7, 2, ssA0,ssA1))   // g27
    PHASE(0,1,1,0, , )                                             // g28
    PHASE(1,0,0,1, , )                                             // g29
    PHASE(1,1,0,0, , )                                             // g30
    PHASE(1,0,1,1, , )                                             // g31
    PHASE(1,1,1,0, , )                                             // g32

    // ---- norms: 4-lane group reduce, publish via LDS ----------------------
    ssA0 += __shfl_xor(ssA0, 1); ssA0 += __shfl_xor(ssA0, 2);
    ssA1 += __shfl_xor(ssA1, 1); ssA1 += __shfl_xor(ssA1, 2);
    ssB0 += __shfl_xor(ssB0, 1); ssB0 += __shfl_xor(ssB0, 2);
    ssB1 += __shfl_xor(ssB1, 1); ssB1 += __shfl_xor(ssB1, 2);

    float* rxs = (float*)sm;          // [256] block-local A-row inv norms
    float* rys = rxs + 256;           // [256] block-local B-row inv norms
    __syncthreads();                  // main-loop LDS fully retired
    if ((lane & 3) == 0) {
        const int r = wave * 16 + (lane >> 2);
        rxs[r]       = 1.0f / sqrtf(ssA0);   // norms ~22.6, eps never binds
        rxs[r + 128] = 1.0f / sqrtf(ssA1);
        rys[r]       = 1.0f / sqrtf(ssB0);
        rys[r + 128] = 1.0f / sqrtf(ssB1);
    }
    __syncthreads();

    // ---- epilogue: C/D layout col=lane&15, row=(lane>>4)*4+j  [m89] -------
    const int col = lane & 15;
    const int r4  = (lane >> 4) * 4;
    const int lm0 = wm * 128;                 // block-local row base
    const int ln0 = wn * 64;                  // block-local col base
    const int gm0 = bm * 256 + lm0;
    const int gn0 = bn * 256 + ln0;
    float* C = out + (size_t)b * NROW * NROW;

    float ryv[4];
#pragma unroll
    for (int n = 0; n < 4; ++n) ryv[n] = rys[ln0 + n * 16 + col];

#pragma unroll
    for (int m = 0; m < 8; ++m) {
#pragma unroll
        for (int j = 0; j < 4; ++j) {
            const int lr = lm0 + m * 16 + r4 + j;
            const float rx = rxs[lr];
            float* Crow = C + (size_t)(gm0 + m * 16 + r4 + j) * NROW + gn0;
#pragma unroll
            for (int n = 0; n < 4; ++n)
                Crow[n * 16 + col] = acc[m][n][j] * rx * ryv[n];
        }
    }
}

extern "C" void kernel_launch(void* const* d_in, const int* in_sizes, int n_in,
                              void* d_out, int out_size, void* d_ws, size_t ws_size,
                              hipStream_t stream)
{
    const float* x = (const float*)d_in[0];
    const float* y = (const float*)d_in[1];
    float* out = (float*)d_out;

    static bool attr_done = false;
    if (!attr_done) {
        hipFuncSetAttribute((const void*)fused_kernel,
                            hipFuncAttributeMaxDynamicSharedMemorySize, 131072);
        attr_done = true;
    }

    fused_kernel<<<dim3(512), 512, 131072, stream>>>(x, y, out);
}

// Round 6
// 243.021 us; speedup vs baseline: 1.0719x; 1.0719x over previous
//
#include <hip/hip_runtime.h>

#define BATCH 8
#define NROW  2048
#define DIM   512

typedef __bf16 bf16x8 __attribute__((ext_vector_type(8)));
typedef float  f32x4  __attribute__((ext_vector_type(4)));
typedef unsigned short u16x8 __attribute__((ext_vector_type(8)));

// round-to-nearest-even fp32 -> bf16 bits (same numerics as passing rounds)
__device__ __forceinline__ unsigned short f2bf(float f) {
    unsigned int u = __float_as_uint(f);
    u += 0x7FFFu + ((u >> 16) & 1u);
    return (unsigned short)(u >> 16);
}

// ---- fused cast+norm+GEMM: 256x256 tile, BK=64, 8 waves, 8-phase pipeline,
// reg-staged fp32->bf16 with load->use distance of 3 phases, 3 slots,
// consume-then-refill (W before L each phase). LDS layout identical to the
// verified round-4/5 kernels: 8 half-buffers of 16KB, idx (par<<2)|(X<<1)|K,
// 16 subtiles [16r][32 bf16], st_16x32 swizzle via pre-swizzled source col.

// load 16 fp32 (2 rows x 8) for half (X,K) of tile T into slot S
#define LOADH(P0, P1, K, T, S) {                                             \
    st[S][0] = *(const f32x4*)((P0) + (T) * 64 + (K) * 32);                  \
    st[S][1] = *(const f32x4*)((P0) + (T) * 64 + (K) * 32 + 4);              \
    st[S][2] = *(const f32x4*)((P1) + (T) * 64 + (K) * 32);                  \
    st[S][3] = *(const f32x4*)((P1) + (T) * 64 + (K) * 32 + 4);              \
  }

// convert slot S -> bf16, accumulate sumsq, ds_write to half (Xi,K) of tile T
#define WRITEH(Xi, K, T, S, SSa, SSb) {                                      \
    char* hb_ = sm + (((((T) & 1) << 2) | ((Xi) << 1) | (K)) << 14);         \
    u16x8 w0_, w1_;                                                          \
    _Pragma("unroll")                                                        \
    for (int j_ = 0; j_ < 4; ++j_) {                                         \
      float v0_ = st[S][0][j_], v1_ = st[S][1][j_];                          \
      float v2_ = st[S][2][j_], v3_ = st[S][3][j_];                          \
      SSa += v0_ * v0_ + v1_ * v1_;                                          \
      SSb += v2_ * v2_ + v3_ * v3_;                                          \
      w0_[j_] = f2bf(v0_); w0_[j_ + 4] = f2bf(v1_);                          \
      w1_[j_] = f2bf(v2_); w1_[j_ + 4] = f2bf(v3_);                          \
    }                                                                        \
    *(u16x8*)(hb_ + swb) = w0_;                                              \
    *(u16x8*)(hb_ + 8192 + swb) = w1_;                                       \
  }

#define LDSA(M, KS, PAR) \
  (*(const bf16x8*)(sm + ((((PAR) << 2) | (KS)) << 14) + ((wm * 8 + (M)) << 10) + rb))
#define LDSB(N, KS, PAR) \
  (*(const bf16x8*)(sm + ((((PAR) << 2) | 2 | (KS)) << 14) + ((wn * 4 + (N)) << 10) + rb))

// one phase: ds-read frags | consume slot (cvt+ds_write) | refill slot | MFMA
#define PHASE(PAR, MH, KS, READB, WSTMT, LSTMT)                              \
  { __builtin_amdgcn_sched_barrier(0);                                       \
    bf16x8 a0 = LDSA((MH)*4+0, KS, PAR), a1 = LDSA((MH)*4+1, KS, PAR),       \
           a2 = LDSA((MH)*4+2, KS, PAR), a3 = LDSA((MH)*4+3, KS, PAR);       \
    if (READB) { bfr[0] = LDSB(0, KS, PAR); bfr[1] = LDSB(1, KS, PAR);       \
                 bfr[2] = LDSB(2, KS, PAR); bfr[3] = LDSB(3, KS, PAR); }     \
    WSTMT;                                                                   \
    LSTMT;                                                                   \
    asm volatile("s_waitcnt lgkmcnt(0)" ::: "memory");                       \
    __builtin_amdgcn_sched_barrier(0);                                       \
    __builtin_amdgcn_s_barrier();                                            \
    __builtin_amdgcn_s_setprio(1);                                           \
    _Pragma("unroll")                                                        \
    for (int n = 0; n < 4; ++n) {                                            \
      acc[(MH)*4+0][n] = __builtin_amdgcn_mfma_f32_16x16x32_bf16(a0, bfr[n], acc[(MH)*4+0][n], 0, 0, 0); \
      acc[(MH)*4+1][n] = __builtin_amdgcn_mfma_f32_16x16x32_bf16(a1, bfr[n], acc[(MH)*4+1][n], 0, 0, 0); \
      acc[(MH)*4+2][n] = __builtin_amdgcn_mfma_f32_16x16x32_bf16(a2, bfr[n], acc[(MH)*4+2][n], 0, 0, 0); \
      acc[(MH)*4+3][n] = __builtin_amdgcn_mfma_f32_16x16x32_bf16(a3, bfr[n], acc[(MH)*4+3][n], 0, 0, 0); \
    }                                                                        \
    __builtin_amdgcn_s_setprio(0);                                           \
    __builtin_amdgcn_sched_barrier(0);                                       \
    __builtin_amdgcn_s_barrier(); }

__global__ __launch_bounds__(512, 2) void fused_kernel(
    const float* __restrict__ x, const float* __restrict__ y,
    float* __restrict__ out)
{
    extern __shared__ char sm[];
    const int tid  = threadIdx.x;
    const int lane = tid & 63;
    const int wave = tid >> 6;
    const int wm   = wave >> 2;     // 0..1  (M half)
    const int wn   = wave & 3;      // 0..3  (N quarter)

    // bijective XCD swizzle: nwg=512, 8 XCDs, 64 blocks each -> batch b == XCD
    const int bid = blockIdx.x;
    const int wg  = (bid & 7) * 64 + (bid >> 3);
    const int b   = wg >> 6;
    const int bm  = (wg >> 3) & 7;
    const int bn  = wg & 7;

    const float* Af = x + ((size_t)b * NROW + bm * 256) * DIM;
    const float* Bf = y + ((size_t)b * NROW + bn * 256) * DIM;

    // staging geometry (same LDS bytes as verified rounds)
    const int vr0 = wave * 16 + (lane >> 2);                     // rows 0..127
    const int vc  = ((lane & 3) * 8) ^ ((lane & 32) ? 16 : 0);   // pre-swizzled k
    const int swb = wave * 1024 + lane * 16;                     // ds_write base
    const int rb  = (lane & 15) * 64 + (((lane >> 4) * 16) ^ ((lane & 8) ? 32 : 0));

    // base pointers: all per-phase global offsets are compile-time immediates
    const float* pA0 = Af + (size_t)vr0 * DIM + vc;
    const float* pA1 = pA0 + (size_t)128 * DIM;
    const float* pB0 = Bf + (size_t)vr0 * DIM + vc;
    const float* pB1 = pB0 + (size_t)128 * DIM;

    f32x4 st[3][4];
    float ssA0 = 0.f, ssA1 = 0.f, ssB0 = 0.f, ssB1 = 0.f;
    f32x4 acc[8][4] = {};
    bf16x8 bfr[4];

    // ---- prologue (load stream pos1..7 = B00 A00 B10 A10 B01 A01 B11,
    //      slot = pos%3; write pos k before load pos k+3) ------------------
    LOADH(pB0, pB1, 0, 0, 1)  LOADH(pA0, pA1, 0, 0, 2)  LOADH(pB0, pB1, 1, 0, 0)
    WRITEH(1, 0, 0, 1, ssB0, ssB1)
    LOADH(pA0, pA1, 1, 0, 1)
    WRITEH(0, 0, 0, 2, ssA0, ssA1)
    LOADH(pB0, pB1, 0, 1, 2)
    WRITEH(1, 1, 0, 0, ssB0, ssB1)
    LOADH(pA0, pA1, 0, 1, 0)
    WRITEH(0, 1, 0, 1, ssA0, ssA1)
    LOADH(pB0, pB1, 1, 1, 1)
    asm volatile("s_waitcnt lgkmcnt(0)" ::: "memory");
    __builtin_amdgcn_sched_barrier(0);
    __builtin_amdgcn_s_barrier();

    // ---- main loop: 32 phases; phase g: W slot (g+1)%3 (load from g-3),
    //      then L same slot (for g+3). Verified: writes >=3 phases before
    //      first read; rewrites >=4 phases after last read. ----------------
    // tile0 (par0)
    PHASE(0,0,0,1, WRITEH(1,0,1, 2, ssB0,ssB1), LOADH(pA0,pA1,1,1, 2))  // g1
    PHASE(0,1,0,0, WRITEH(0,0,1, 0, ssA0,ssA1), LOADH(pB0,pB1,0,2, 0))  // g2
    PHASE(0,0,1,1, WRITEH(1,1,1, 1, ssB0,ssB1), LOADH(pA0,pA1,0,2, 1))  // g3
    PHASE(0,1,1,0, WRITEH(0,1,1, 2, ssA0,ssA1), LOADH(pB0,pB1,1,2, 2))  // g4
    // tile1 (par1)
    PHASE(1,0,0,1, WRITEH(1,0,2, 0, ssB0,ssB1), LOADH(pA0,pA1,1,2, 0))  // g5
    PHASE(1,1,0,0, WRITEH(0,0,2, 1, ssA0,ssA1), LOADH(pB0,pB1,0,3, 1))  // g6
    PHASE(1,0,1,1, WRITEH(1,1,2, 2, ssB0,ssB1), LOADH(pA0,pA1,0,3, 2))  // g7
    PHASE(1,1,1,0, WRITEH(0,1,2, 0, ssA0,ssA1), LOADH(pB0,pB1,1,3, 0))  // g8
    // tile2 (par0)
    PHASE(0,0,0,1, WRITEH(1,0,3, 1, ssB0,ssB1), LOADH(pA0,pA1,1,3, 1))  // g9
    PHASE(0,1,0,0, WRITEH(0,0,3, 2, ssA0,ssA1), LOADH(pB0,pB1,0,4, 2))  // g10
    PHASE(0,0,1,1, WRITEH(1,1,3, 0, ssB0,ssB1), LOADH(pA0,pA1,0,4, 0))  // g11
    PHASE(0,1,1,0, WRITEH(0,1,3, 1, ssA0,ssA1), LOADH(pB0,pB1,1,4, 1))  // g12
    // tile3 (par1)
    PHASE(1,0,0,1, WRITEH(1,0,4, 2, ssB0,ssB1), LOADH(pA0,pA1,1,4, 2))  // g13
    PHASE(1,1,0,0, WRITEH(0,0,4, 0, ssA0,ssA1), LOADH(pB0,pB1,0,5, 0))  // g14
    PHASE(1,0,1,1, WRITEH(1,1,4, 1, ssB0,ssB1), LOADH(pA0,pA1,0,5, 1))  // g15
    PHASE(1,1,1,0, WRITEH(0,1,4, 2, ssA0,ssA1), LOADH(pB0,pB1,1,5, 2))  // g16
    // tile4 (par0)
    PHASE(0,0,0,1, WRITEH(1,0,5, 0, ssB0,ssB1), LOADH(pA0,pA1,1,5, 0))  // g17
    PHASE(0,1,0,0, WRITEH(0,0,5, 1, ssA0,ssA1), LOADH(pB0,pB1,0,6, 1))  // g18
    PHASE(0,0,1,1, WRITEH(1,1,5, 2, ssB0,ssB1), LOADH(pA0,pA1,0,6, 2))  // g19
    PHASE(0,1,1,0, WRITEH(0,1,5, 0, ssA0,ssA1), LOADH(pB0,pB1,1,6, 0))  // g20
    // tile5 (par1)
    PHASE(1,0,0,1, WRITEH(1,0,6, 1, ssB0,ssB1), LOADH(pA0,pA1,1,6, 1))  // g21
    PHASE(1,1,0,0, WRITEH(0,0,6, 2, ssA0,ssA1), LOADH(pB0,pB1,0,7, 2))  // g22
    PHASE(1,0,1,1, WRITEH(1,1,6, 0, ssB0,ssB1), LOADH(pA0,pA1,0,7, 0))  // g23
    PHASE(1,1,1,0, WRITEH(0,1,6, 1, ssA0,ssA1), LOADH(pB0,pB1,1,7, 1))  // g24
    // tile6 (par0)
    PHASE(0,0,0,1, WRITEH(1,0,7, 2, ssB0,ssB1), LOADH(pA0,pA1,1,7, 2))  // g25
    PHASE(0,1,0,0, WRITEH(0,0,7, 0, ssA0,ssA1), )                       // g26
    PHASE(0,0,1,1, WRITEH(1,1,7, 1, ssB0,ssB1), )                       // g27
    PHASE(0,1,1,0, WRITEH(0,1,7, 2, ssA0,ssA1), )                       // g28
    // tile7 (par1)
    PHASE(1,0,0,1, , )                                                  // g29
    PHASE(1,1,0,0, , )                                                  // g30
    PHASE(1,0,1,1, , )                                                  // g31
    PHASE(1,1,1,0, , )                                                  // g32

    // ---- norms: 4-lane group reduce, publish via LDS ----------------------
    ssA0 += __shfl_xor(ssA0, 1); ssA0 += __shfl_xor(ssA0, 2);
    ssA1 += __shfl_xor(ssA1, 1); ssA1 += __shfl_xor(ssA1, 2);
    ssB0 += __shfl_xor(ssB0, 1); ssB0 += __shfl_xor(ssB0, 2);
    ssB1 += __shfl_xor(ssB1, 1); ssB1 += __shfl_xor(ssB1, 2);

    float* rxs = (float*)sm;          // [256] block-local A-row inv norms
    float* rys = rxs + 256;           // [256] block-local B-row inv norms
    __syncthreads();                  // main-loop LDS fully retired
    if ((lane & 3) == 0) {
        const int r = wave * 16 + (lane >> 2);
        rxs[r]       = 1.0f / sqrtf(ssA0);   // norms ~22.6, eps never binds
        rxs[r + 128] = 1.0f / sqrtf(ssA1);
        rys[r]       = 1.0f / sqrtf(ssB0);
        rys[r + 128] = 1.0f / sqrtf(ssB1);
    }
    __syncthreads();

    // ---- epilogue: C/D layout col=lane&15, row=(lane>>4)*4+j  [m89] -------
    const int col = lane & 15;
    const int r4  = (lane >> 4) * 4;
    const int lm0 = wm * 128;
    const int ln0 = wn * 64;
    const int gm0 = bm * 256 + lm0;
    const int gn0 = bn * 256 + ln0;
    float* C = out + (size_t)b * NROW * NROW;

    float ryv[4];
#pragma unroll
    for (int n = 0; n < 4; ++n) ryv[n] = rys[ln0 + n * 16 + col];

#pragma unroll
    for (int m = 0; m < 8; ++m) {
#pragma unroll
        for (int j = 0; j < 4; ++j) {
            const int lr = lm0 + m * 16 + r4 + j;
            const float rx = rxs[lr];
            float* Crow = C + (size_t)(gm0 + m * 16 + r4 + j) * NROW + gn0;
#pragma unroll
            for (int n = 0; n < 4; ++n)
                Crow[n * 16 + col] = acc[m][n][j] * rx * ryv[n];
        }
    }
}

extern "C" void kernel_launch(void* const* d_in, const int* in_sizes, int n_in,
                              void* d_out, int out_size, void* d_ws, size_t ws_size,
                              hipStream_t stream)
{
    const float* x = (const float*)d_in[0];
    const float* y = (const float*)d_in[1];
    float* out = (float*)d_out;

    static bool attr_done = false;
    if (!attr_done) {
        hipFuncSetAttribute((const void*)fused_kernel,
                            hipFuncAttributeMaxDynamicSharedMemorySize, 131072);
        attr_done = true;
    }

    fused_kernel<<<dim3(512), 512, 131072, stream>>>(x, y, out);
}

// Round 7
// 224.427 us; speedup vs baseline: 1.1607x; 1.0829x over previous
//
#include <hip/hip_runtime.h>

#define BATCH 8
#define NROW  2048
#define DIM   512

typedef __bf16 bf16x8 __attribute__((ext_vector_type(8)));
typedef float  f32x4  __attribute__((ext_vector_type(4)));

typedef __attribute__((address_space(3))) void       lds_t;
typedef const __attribute__((address_space(1))) void gmem_t;

// round-to-nearest-even fp32 -> bf16 bits
__device__ __forceinline__ unsigned short f2bf(float f) {
    unsigned int u = __float_as_uint(f);
    u += 0x7FFFu + ((u >> 16) & 1u);
    return (unsigned short)(u >> 16);
}

// One wave per row: cast row to bf16 (coalesced) + compute 1/||row|| in fp32.
__global__ __launch_bounds__(256) void prep_kernel(
    const float* __restrict__ x, const float* __restrict__ y,
    unsigned short* __restrict__ xbf, unsigned short* __restrict__ ybf,
    float* __restrict__ rxn, float* __restrict__ ryn)
{
    const int wave = threadIdx.x >> 6;
    const int lane = threadIdx.x & 63;
    const int row  = blockIdx.x * 4 + wave;

    const float* src; unsigned short* dst; float* rn;
    if (blockIdx.y == 0) { src = x; dst = xbf; rn = rxn; }
    else                 { src = y; dst = ybf; rn = ryn; }

    const float4* s4 = (const float4*)(src + (size_t)row * DIM);
    ushort4*      d4 = (ushort4*)(dst + (size_t)row * DIM);

    float ss = 0.f;
#pragma unroll
    for (int h = 0; h < 2; ++h) {
        float4 v = s4[h * 64 + lane];
        ss += v.x * v.x + v.y * v.y + v.z * v.z + v.w * v.w;
        ushort4 o;
        o.x = f2bf(v.x); o.y = f2bf(v.y); o.z = f2bf(v.z); o.w = f2bf(v.w);
        d4[h * 64 + lane] = o;
    }
#pragma unroll
    for (int off = 32; off; off >>= 1) ss += __shfl_xor(ss, off, 64);
    if (lane == 0) rn[row] = 1.0f / sqrtf(ss);   // norms ~22.6, eps never binds
}

// ---------------- 256x256 tile, BK=64, 8-wave, 8-phase pipelined GEMM -------
// TILE-PAIRED: each block computes two adjacent N-tiles (bn0, bn0+1) so the
// first tile's C-stores drain under the second tile's prologue/compute and
// one ramp is saved. Schedule/LDS identical to the verified round-4 kernel.
// LDS: 8 half-buffers of 16KB: index (par<<2)|(X<<1)|k, X: A=0,B=1.
// Half layout: 16 subtiles [16r][32 bf16] of 1024B, st_16x32 swizzle via
// pre-swizzled per-lane GLOBAL source (linear gload_lds dest, rule #21).

#define STAGE(Xp, Xi, K, T)                                                  \
  { char* hb_ = sm + (((((T) & 1) << 2) | ((Xi) << 1) | (K)) << 14);         \
    __builtin_amdgcn_global_load_lds(                                        \
      (gmem_t*)((Xp) + (size_t)vr0 * DIM + (T) * 64 + (K) * 32 + vc),        \
      (lds_t*)(hb_ + wave * 1024), 16, 0, 0);                                \
    __builtin_amdgcn_global_load_lds(                                        \
      (gmem_t*)((Xp) + (size_t)vr1 * DIM + (T) * 64 + (K) * 32 + vc),        \
      (lds_t*)(hb_ + 8192 + wave * 1024), 16, 0, 0); }

#define LDSA(M, KS, PAR) \
  (*(const bf16x8*)(sm + ((((PAR) << 2) | (KS)) << 14) + ((wm * 8 + (M)) << 10) + rb))
#define LDSB(N, KS, PAR) \
  (*(const bf16x8*)(sm + ((((PAR) << 2) | 2 | (KS)) << 14) + ((wn * 4 + (N)) << 10) + rb))

#define PHASE(PAR, MH, KS, READB, STAGE_STMT, VM_STMT)                       \
  { __builtin_amdgcn_sched_barrier(0);                                       \
    bf16x8 a0 = LDSA((MH)*4+0, KS, PAR), a1 = LDSA((MH)*4+1, KS, PAR),       \
           a2 = LDSA((MH)*4+2, KS, PAR), a3 = LDSA((MH)*4+3, KS, PAR);       \
    if (READB) { bfr[0] = LDSB(0, KS, PAR); bfr[1] = LDSB(1, KS, PAR);       \
                 bfr[2] = LDSB(2, KS, PAR); bfr[3] = LDSB(3, KS, PAR); }     \
    STAGE_STMT;                                                              \
    __builtin_amdgcn_s_barrier();                                            \
    asm volatile("s_waitcnt lgkmcnt(0)" ::: "memory");                       \
    VM_STMT;                                                                 \
    __builtin_amdgcn_sched_barrier(0);                                       \
    __builtin_amdgcn_s_setprio(1);                                           \
    _Pragma("unroll")                                                        \
    for (int n = 0; n < 4; ++n) {                                            \
      acc[(MH)*4+0][n] = __builtin_amdgcn_mfma_f32_16x16x32_bf16(a0, bfr[n], acc[(MH)*4+0][n], 0, 0, 0); \
      acc[(MH)*4+1][n] = __builtin_amdgcn_mfma_f32_16x16x32_bf16(a1, bfr[n], acc[(MH)*4+1][n], 0, 0, 0); \
      acc[(MH)*4+2][n] = __builtin_amdgcn_mfma_f32_16x16x32_bf16(a2, bfr[n], acc[(MH)*4+2][n], 0, 0, 0); \
      acc[(MH)*4+3][n] = __builtin_amdgcn_mfma_f32_16x16x32_bf16(a3, bfr[n], acc[(MH)*4+3][n], 0, 0, 0); \
    }                                                                        \
    __builtin_amdgcn_s_setprio(0);                                           \
    __builtin_amdgcn_sched_barrier(0);                                       \
    __builtin_amdgcn_s_barrier(); }

#define VM6 asm volatile("s_waitcnt vmcnt(6)" ::: "memory")
#define VM0 asm volatile("s_waitcnt vmcnt(0)" ::: "memory")

__global__ __launch_bounds__(512) void gemm_kernel(
    const __bf16* __restrict__ xbf, const __bf16* __restrict__ ybf,
    const float* __restrict__ rxn, const float* __restrict__ ryn,
    float* __restrict__ out)
{
    extern __shared__ char sm[];
    const int tid  = threadIdx.x;
    const int lane = tid & 63;
    const int wave = tid >> 6;
    const int wm   = wave >> 2;     // 0..1  (M half)
    const int wn   = wave & 3;      // 0..3  (N quarter)

    // grid 256 = 8 batches x 8 bm x 4 bn-pairs; bid&7 == batch == XCD
    // (per-XCD working set: 8 A-panels + 8 B-panels x 256KB = 4MB = L2)
    const int bid = blockIdx.x;
    const int b   = bid & 7;
    const int p   = bid >> 3;       // 0..31
    const int bm  = p >> 2;         // 0..7
    const int bn0 = (p & 3) << 1;   // 0,2,4,6

    const __bf16* Ap = xbf + ((size_t)b * NROW + bm * 256) * DIM;

    // staging per-lane source geometry (inverse-swizzled global address)
    const int vr0 = wave * 16 + (lane >> 2);          // rows 0..127
    const int vr1 = vr0 + 128;                        // rows 128..255
    const int vc  = ((lane & 3) * 8) ^ ((lane & 32) ? 16 : 0);   // bf16 units
    const int rb  = (lane & 15) * 64 + (((lane >> 4) * 16) ^ ((lane & 8) ? 32 : 0));

    // epilogue constants (C/D layout col=lane&15, row=(lane>>4)*4+j  [m89])
    const int col = lane & 15;
    const int r4  = (lane >> 4) * 4;
    const int gm0 = bm * 256 + wm * 128;
    float* C = out + (size_t)b * NROW * NROW;
    const float* rxb = rxn + b * NROW;
    const float* ryb = ryn + b * NROW;

#pragma unroll
    for (int h = 0; h < 2; ++h) {
        const int bn = bn0 + h;
        const __bf16* Bp = ybf + ((size_t)b * NROW + bn * 256) * DIM;

        // ---- prologue: B-k0(0) A-k0(0) B-k1(0) A-k1(0) B-k0(1) A-k0(1) B-k1(1)
        STAGE(Bp, 1, 0, 0) STAGE(Ap, 0, 0, 0) STAGE(Bp, 1, 1, 0) STAGE(Ap, 0, 1, 0)
        STAGE(Bp, 1, 0, 1) STAGE(Ap, 0, 0, 1) STAGE(Bp, 1, 1, 1)
        VM6;   // on h=1 this also drains tile0's in-flight C-stores (bounded)
        __builtin_amdgcn_sched_barrier(0);
        __builtin_amdgcn_s_barrier();

        f32x4 acc[8][4] = {};
        bf16x8 bfr[4];

        for (int i = 0; i < 4; ++i) {
            const int t1 = 2 * i + 1, t2 = 2 * i + 2, t3 = 2 * i + 3;
            const bool full = (i < 3);
            // tile T0 = 2i (par 0)
            PHASE(0, 0, 0, 1, STAGE(Ap, 0, 1, t1), )
            PHASE(0, 1, 0, 0, if (full) STAGE(Bp, 1, 0, t2), )
            PHASE(0, 0, 1, 1, if (full) STAGE(Ap, 0, 0, t2), )
            PHASE(0, 1, 1, 0, if (full) STAGE(Bp, 1, 1, t2), if (full) { VM6; } else { VM0; })
            // tile T1 = 2i+1 (par 1)
            PHASE(1, 0, 0, 1, if (full) STAGE(Ap, 0, 1, t2), )
            PHASE(1, 1, 0, 0, if (full) STAGE(Bp, 1, 0, t3), )
            PHASE(1, 0, 1, 1, if (full) STAGE(Ap, 0, 0, t3), )
            PHASE(1, 1, 1, 0, if (full) STAGE(Bp, 1, 1, t3), if (full) { VM6; })
        }

        // ---- epilogue for this bn: stores issued with no wait; they drain
        // under the next tile's prologue/compute (h=0) or kernel end (h=1).
        const int gn0 = bn * 256 + wn * 64;
        float ryv[4];
#pragma unroll
        for (int n = 0; n < 4; ++n) ryv[n] = ryb[gn0 + n * 16 + col];

#pragma unroll
        for (int m = 0; m < 8; ++m) {
#pragma unroll
            for (int j = 0; j < 4; ++j) {
                const int gm = gm0 + m * 16 + r4 + j;
                const float rx = rxb[gm];
                float* Crow = C + (size_t)gm * NROW + gn0;
#pragma unroll
                for (int n = 0; n < 4; ++n)
                    Crow[n * 16 + col] = acc[m][n][j] * rx * ryv[n];
            }
        }
    }
}

extern "C" void kernel_launch(void* const* d_in, const int* in_sizes, int n_in,
                              void* d_out, int out_size, void* d_ws, size_t ws_size,
                              hipStream_t stream)
{
    const float* x = (const float*)d_in[0];
    const float* y = (const float*)d_in[1];
    float* out = (float*)d_out;

    char* ws = (char*)d_ws;
    unsigned short* xbf = (unsigned short*)ws;                            // 16 MiB
    unsigned short* ybf = (unsigned short*)(ws + ((size_t)16 << 20));     // 16 MiB
    float* rxn = (float*)(ws + ((size_t)32 << 20));                       // 64 KiB
    float* ryn = rxn + BATCH * NROW;                                      // 64 KiB

    static bool attr_done = false;
    if (!attr_done) {
        hipFuncSetAttribute((const void*)gemm_kernel,
                            hipFuncAttributeMaxDynamicSharedMemorySize, 131072);
        attr_done = true;
    }

    prep_kernel<<<dim3(4096, 2), 256, 0, stream>>>(x, y, xbf, ybf, rxn, ryn);
    gemm_kernel<<<dim3(256), 512, 131072, stream>>>(
        (const __bf16*)xbf, (const __bf16*)ybf, rxn, ryn, out);
}

// Round 8
// 215.608 us; speedup vs baseline: 1.2082x; 1.0409x over previous
//
#include <hip/hip_runtime.h>

#define BATCH 8
#define NROW  2048
#define DIM   512

typedef __bf16 bf16x8 __attribute__((ext_vector_type(8)));
typedef float  f32x4  __attribute__((ext_vector_type(4)));

typedef __attribute__((address_space(3))) void       lds_t;
typedef const __attribute__((address_space(1))) void gmem_t;

// round-to-nearest-even fp32 -> bf16 bits
__device__ __forceinline__ unsigned short f2bf(float f) {
    unsigned int u = __float_as_uint(f);
    u += 0x7FFFu + ((u >> 16) & 1u);
    return (unsigned short)(u >> 16);
}

// One wave per row: cast row to bf16 (coalesced) + compute 1/||row|| in fp32.
__global__ __launch_bounds__(256) void prep_kernel(
    const float* __restrict__ x, const float* __restrict__ y,
    unsigned short* __restrict__ xbf, unsigned short* __restrict__ ybf,
    float* __restrict__ rxn, float* __restrict__ ryn)
{
    const int wave = threadIdx.x >> 6;
    const int lane = threadIdx.x & 63;
    const int row  = blockIdx.x * 4 + wave;

    const float* src; unsigned short* dst; float* rn;
    if (blockIdx.y == 0) { src = x; dst = xbf; rn = rxn; }
    else                 { src = y; dst = ybf; rn = ryn; }

    const float4* s4 = (const float4*)(src + (size_t)row * DIM);
    ushort4*      d4 = (ushort4*)(dst + (size_t)row * DIM);

    float ss = 0.f;
#pragma unroll
    for (int h = 0; h < 2; ++h) {
        float4 v = s4[h * 64 + lane];
        ss += v.x * v.x + v.y * v.y + v.z * v.z + v.w * v.w;
        ushort4 o;
        o.x = f2bf(v.x); o.y = f2bf(v.y); o.z = f2bf(v.z); o.w = f2bf(v.w);
        d4[h * 64 + lane] = o;
    }
#pragma unroll
    for (int off = 32; off; off >>= 1) ss += __shfl_xor(ss, off, 64);
    if (lane == 0) rn[row] = 1.0f / sqrtf(ss);   // norms ~22.6, eps never binds
}

// ---------------- 256x256 tile, BK=64, 8-wave, 8-phase pipelined GEMM -------
// (exact round-4 configuration: best measured, 215.5 us total)
// LDS: 8 half-buffers of 16KB: index (par<<2)|(X<<1)|k, X: A=0,B=1.
// Half-buffer layout: 16 subtiles [16 rows][32 bf16] of 1024B, st_16x32
// swizzle: col-bytes ^= 32 when (row&15)>=8. Staged via linear-dest
// global_load_lds with inverse-swizzled per-lane GLOBAL source (rule #21).

#define STAGE(Xp, Xi, K, T)                                                  \
  { char* hb_ = sm + (((((T) & 1) << 2) | ((Xi) << 1) | (K)) << 14);         \
    __builtin_amdgcn_global_load_lds(                                        \
      (gmem_t*)((Xp) + (size_t)vr0 * DIM + (T) * 64 + (K) * 32 + vc),        \
      (lds_t*)(hb_ + wave * 1024), 16, 0, 0);                                \
    __builtin_amdgcn_global_load_lds(                                        \
      (gmem_t*)((Xp) + (size_t)vr1 * DIM + (T) * 64 + (K) * 32 + vc),        \
      (lds_t*)(hb_ + 8192 + wave * 1024), 16, 0, 0); }

#define LDSA(M, KS, PAR) \
  (*(const bf16x8*)(sm + ((((PAR) << 2) | (KS)) << 14) + ((wm * 8 + (M)) << 10) + rb))
#define LDSB(N, KS, PAR) \
  (*(const bf16x8*)(sm + ((((PAR) << 2) | 2 | (KS)) << 14) + ((wn * 4 + (N)) << 10) + rb))

#define PHASE(PAR, MH, KS, READB, STAGE_STMT, VM_STMT)                       \
  { __builtin_amdgcn_sched_barrier(0);                                       \
    bf16x8 a0 = LDSA((MH)*4+0, KS, PAR), a1 = LDSA((MH)*4+1, KS, PAR),       \
           a2 = LDSA((MH)*4+2, KS, PAR), a3 = LDSA((MH)*4+3, KS, PAR);       \
    if (READB) { bfr[0] = LDSB(0, KS, PAR); bfr[1] = LDSB(1, KS, PAR);       \
                 bfr[2] = LDSB(2, KS, PAR); bfr[3] = LDSB(3, KS, PAR); }     \
    STAGE_STMT;                                                              \
    __builtin_amdgcn_s_barrier();                                            \
    asm volatile("s_waitcnt lgkmcnt(0)" ::: "memory");                       \
    VM_STMT;                                                                 \
    __builtin_amdgcn_sched_barrier(0);                                       \
    __builtin_amdgcn_s_setprio(1);                                           \
    _Pragma("unroll")                                                        \
    for (int n = 0; n < 4; ++n) {                                            \
      acc[(MH)*4+0][n] = __builtin_amdgcn_mfma_f32_16x16x32_bf16(a0, bfr[n], acc[(MH)*4+0][n], 0, 0, 0); \
      acc[(MH)*4+1][n] = __builtin_amdgcn_mfma_f32_16x16x32_bf16(a1, bfr[n], acc[(MH)*4+1][n], 0, 0, 0); \
      acc[(MH)*4+2][n] = __builtin_amdgcn_mfma_f32_16x16x32_bf16(a2, bfr[n], acc[(MH)*4+2][n], 0, 0, 0); \
      acc[(MH)*4+3][n] = __builtin_amdgcn_mfma_f32_16x16x32_bf16(a3, bfr[n], acc[(MH)*4+3][n], 0, 0, 0); \
    }                                                                        \
    __builtin_amdgcn_s_setprio(0);                                           \
    __builtin_amdgcn_sched_barrier(0);                                       \
    __builtin_amdgcn_s_barrier(); }

#define VM6 asm volatile("s_waitcnt vmcnt(6)" ::: "memory")
#define VM0 asm volatile("s_waitcnt vmcnt(0)" ::: "memory")

__global__ __launch_bounds__(512) void gemm_kernel(
    const __bf16* __restrict__ xbf, const __bf16* __restrict__ ybf,
    const float* __restrict__ rxn, const float* __restrict__ ryn,
    float* __restrict__ out)
{
    extern __shared__ char sm[];
    const int tid  = threadIdx.x;
    const int lane = tid & 63;
    const int wave = tid >> 6;
    const int wm   = wave >> 2;     // 0..1  (M half)
    const int wn   = wave & 3;      // 0..3  (N quarter)

    // bijective XCD swizzle: nwg=512, 8 XCDs, 64 blocks each -> batch b == XCD
    const int bid = blockIdx.x;
    const int wg  = (bid & 7) * 64 + (bid >> 3);
    const int b   = wg >> 6;
    const int bm  = (wg >> 3) & 7;
    const int bn  = wg & 7;

    const __bf16* Ap = xbf + ((size_t)b * NROW + bm * 256) * DIM;
    const __bf16* Bp = ybf + ((size_t)b * NROW + bn * 256) * DIM;

    // staging per-lane source geometry (inverse-swizzled global address)
    const int vr0 = wave * 16 + (lane >> 2);          // rows 0..127
    const int vr1 = vr0 + 128;                        // rows 128..255
    const int vc  = ((lane & 3) * 8) ^ ((lane & 32) ? 16 : 0);   // bf16 units
    // read per-lane base byte within a half-buffer subtile-row
    const int rb  = (lane & 15) * 64 + (((lane >> 4) * 16) ^ ((lane & 8) ? 32 : 0));

    // ---- prologue: B-k0(0) A-k0(0) B-k1(0) A-k1(0) B-k0(1) A-k0(1) B-k1(1)
    STAGE(Bp, 1, 0, 0) STAGE(Ap, 0, 0, 0) STAGE(Bp, 1, 1, 0) STAGE(Ap, 0, 1, 0)
    STAGE(Bp, 1, 0, 1) STAGE(Ap, 0, 0, 1) STAGE(Bp, 1, 1, 1)
    VM6;
    __builtin_amdgcn_sched_barrier(0);
    __builtin_amdgcn_s_barrier();

    f32x4 acc[8][4] = {};
    bf16x8 bfr[4];

    for (int i = 0; i < 4; ++i) {
        const int t1 = 2 * i + 1, t2 = 2 * i + 2, t3 = 2 * i + 3;
        const bool full = (i < 3);
        // tile T0 = 2i (par 0)
        PHASE(0, 0, 0, 1, STAGE(Ap, 0, 1, t1), )
        PHASE(0, 1, 0, 0, if (full) STAGE(Bp, 1, 0, t2), )
        PHASE(0, 0, 1, 1, if (full) STAGE(Ap, 0, 0, t2), )
        PHASE(0, 1, 1, 0, if (full) STAGE(Bp, 1, 1, t2), if (full) { VM6; } else { VM0; })
        // tile T1 = 2i+1 (par 1)
        PHASE(1, 0, 0, 1, if (full) STAGE(Ap, 0, 1, t2), )
        PHASE(1, 1, 0, 0, if (full) STAGE(Bp, 1, 0, t3), )
        PHASE(1, 0, 1, 1, if (full) STAGE(Ap, 0, 0, t3), )
        PHASE(1, 1, 1, 0, if (full) STAGE(Bp, 1, 1, t3), if (full) { VM6; })
    }

    // ---- epilogue: C/D layout col=lane&15, row=(lane>>4)*4+j  [m89]
    const int col = lane & 15;
    const int r4  = (lane >> 4) * 4;
    const int gm0 = bm * 256 + wm * 128;
    const int gn0 = bn * 256 + wn * 64;
    float* C = out + (size_t)b * NROW * NROW;
    const float* rxb = rxn + b * NROW;
    const float* ryb = ryn + b * NROW;

    float ryv[4];
#pragma unroll
    for (int n = 0; n < 4; ++n) ryv[n] = ryb[gn0 + n * 16 + col];

#pragma unroll
    for (int m = 0; m < 8; ++m) {
#pragma unroll
        for (int j = 0; j < 4; ++j) {
            const int gm = gm0 + m * 16 + r4 + j;
            const float rx = rxb[gm];
            float* Crow = C + (size_t)gm * NROW + gn0;
#pragma unroll
            for (int n = 0; n < 4; ++n)
                Crow[n * 16 + col] = acc[m][n][j] * rx * ryv[n];
        }
    }
}

extern "C" void kernel_launch(void* const* d_in, const int* in_sizes, int n_in,
                              void* d_out, int out_size, void* d_ws, size_t ws_size,
                              hipStream_t stream)
{
    const float* x = (const float*)d_in[0];
    const float* y = (const float*)d_in[1];
    float* out = (float*)d_out;

    char* ws = (char*)d_ws;
    unsigned short* xbf = (unsigned short*)ws;                            // 16 MiB
    unsigned short* ybf = (unsigned short*)(ws + ((size_t)16 << 20));     // 16 MiB
    float* rxn = (float*)(ws + ((size_t)32 << 20));                       // 64 KiB
    float* ryn = rxn + BATCH * NROW;                                      // 64 KiB

    static bool attr_done = false;
    if (!attr_done) {
        hipFuncSetAttribute((const void*)gemm_kernel,
                            hipFuncAttributeMaxDynamicSharedMemorySize, 131072);
        attr_done = true;
    }

    prep_kernel<<<dim3(4096, 2), 256, 0, stream>>>(x, y, xbf, ybf, rxn, ryn);
    gemm_kernel<<<dim3(512), 512, 131072, stream>>>(
        (const __bf16*)xbf, (const __bf16*)ybf, rxn, ryn, out);
}